// Round 3
// baseline (284.918 us; speedup 1.0000x reference)
//
#include <hip/hip_runtime.h>

// Problem: B=8, N=1024, C=768, H=12, D=64. Inputs fp32; internal bf16 MFMA.
// ws layout: wqkvT bf16[2304][768] | wprojT bf16[768][768] |
//   q,k bf16[B*H][N][D], vT bf16[B*H][D][N] | aout bf16[8192][768] (aliased as xb)

typedef unsigned short u16;
typedef short s16x8 __attribute__((ext_vector_type(8)));   // 8 bf16 = 4 VGPRs
typedef float f32x4 __attribute__((ext_vector_type(4)));
typedef u16   u16x8 __attribute__((ext_vector_type(8)));
typedef u16   u16x4 __attribute__((ext_vector_type(4)));

__device__ __forceinline__ u16 f2bf(float f) {
    unsigned int u = __builtin_bit_cast(unsigned int, f);
    u += 0x7FFFu + ((u >> 16) & 1u);      // RNE
    return (u16)(u >> 16);
}

// ---------------------------------------------------------------------------
// Fused prep: x fp32->bf16 convert (blocks 0..3071) | w_qkv transpose
// (3072..4799) | w_proj transpose (4800..5375).
// ---------------------------------------------------------------------------
__global__ __launch_bounds__(256) void prep(
    const float* __restrict__ x, u16* __restrict__ xb,
    const float* __restrict__ wq, u16* __restrict__ wqT,
    const float* __restrict__ wp, u16* __restrict__ wpT) {
    __shared__ float ts[32][33];
    const int g = blockIdx.x, tid = threadIdx.x;
    if (g < 3072) {
        const size_t i = ((size_t)g * 256 + tid) * 8;
        float4 v0 = *(const float4*)(x + i);
        float4 v1 = *(const float4*)(x + i + 4);
        u16x8 p;
        p[0] = f2bf(v0.x); p[1] = f2bf(v0.y); p[2] = f2bf(v0.z); p[3] = f2bf(v0.w);
        p[4] = f2bf(v1.x); p[5] = f2bf(v1.y); p[6] = f2bf(v1.z); p[7] = f2bf(v1.w);
        *(u16x8*)(xb + i) = p;
        return;
    }
    const float* in; u16* out; int K, Nc, n0, k0;
    if (g < 4800) {
        int gg = g - 3072; in = wq; out = wqT; K = 768; Nc = 2304;
        n0 = (gg % 72) * 32; k0 = (gg / 72) * 32;
    } else {
        int gg = g - 4800; in = wp; out = wpT; K = 768; Nc = 768;
        n0 = (gg % 24) * 32; k0 = (gg / 24) * 32;
    }
    const int tx = tid & 31, ty = tid >> 5;
#pragma unroll
    for (int j = 0; j < 4; ++j) {
        int r = ty + j * 8;
        ts[r][tx] = in[(size_t)(k0 + r) * Nc + n0 + tx];
    }
    __syncthreads();
#pragma unroll
    for (int j = 0; j < 4; ++j) {
        int r = ty + j * 8;
        out[(size_t)(n0 + r) * K + k0 + tx] = f2bf(ts[tx][r]);
    }
}

// ---------------------------------------------------------------------------
// Barrier-free direct-from-L2 GEMM loop (no LDS, no syncs, no waitcnt asm).
// Rationale: staged operands are L2-resident (wqkvT 3.5MB/XCD-L2, A-stripe
// ~1.6MB/XCD after swizzle; FETCH_SIZE ~= compulsory). LDS round-trip +
// barrier lockstep measured as pure overhead (R0 depth-0 527 TF ~= R2
// counted-dbuf 530 TF; MFMA-busy conserved ~11us; stalls structural).
// Per wave: 64x64 output. Per BK=32 step: 4 A-frag + 4 B-frag b128 loads
// straight to VGPR (16 lanes x 64B-contiguous row chunks = clean sectors),
// reg-double-buffered 1 step ahead; 16 MFMA. Fully unrolled: compiler
// software-pipelines loads under MFMA clusters with its own counted vmcnt.
// Every wave free-runs -> inter-wave overlap without lockstep (m114).
// ---------------------------------------------------------------------------
template<bool SWAP>
__device__ __forceinline__ void mfma16(f32x4 (&acc)[4][4],
                                       const s16x8 (&av)[4], const s16x8 (&bv)[4]) {
#pragma unroll
    for (int ri = 0; ri < 4; ++ri)
#pragma unroll
        for (int ci = 0; ci < 4; ++ci) {
            if (SWAP)   // D = C^T: row=d(quad*4+rg), col=token(m15)
                acc[ri][ci] = __builtin_amdgcn_mfma_f32_16x16x32_bf16(bv[ci], av[ri], acc[ri][ci], 0, 0, 0);
            else        // D = C: row=token(quad*4+rg), col=d/n(m15)
                acc[ri][ci] = __builtin_amdgcn_mfma_f32_16x16x32_bf16(av[ri], bv[ci], acc[ri][ci], 0, 0, 0);
        }
}

template<bool SWAP>
__device__ __forceinline__ void gemm_l2_loop(
    f32x4 (&acc)[4][4], const u16* __restrict__ A, const u16* __restrict__ B,
    int m0, int n0, int lane, int w) {
    const int m15 = lane & 15, quad = lane >> 4;
    const int wy = w >> 1, wx = w & 1;
    const u16* ap[4];
    const u16* bp[4];
#pragma unroll
    for (int ri = 0; ri < 4; ++ri)
        ap[ri] = A + (size_t)(m0 + wy * 64 + ri * 16 + m15) * 768 + quad * 8;
#pragma unroll
    for (int ci = 0; ci < 4; ++ci)
        bp[ci] = B + (size_t)(n0 + wx * 64 + ci * 16 + m15) * 768 + quad * 8;

    s16x8 a0[4], b0[4], a1[4], b1[4];
#pragma unroll
    for (int i = 0; i < 4; ++i) {
        a0[i] = *(const s16x8*)ap[i];
        b0[i] = *(const s16x8*)bp[i];
    }

#pragma unroll
    for (int s = 0; s < 24; s += 2) {
        // prefetch step s+1 while computing s
#pragma unroll
        for (int i = 0; i < 4; ++i) {
            a1[i] = *(const s16x8*)(ap[i] + (s + 1) * 32);
            b1[i] = *(const s16x8*)(bp[i] + (s + 1) * 32);
        }
        mfma16<SWAP>(acc, a0, b0);
        if (s + 2 < 24) {
            // prefetch step s+2 while computing s+1
#pragma unroll
            for (int i = 0; i < 4; ++i) {
                a0[i] = *(const s16x8*)(ap[i] + (s + 2) * 32);
                b0[i] = *(const s16x8*)(bp[i] + (s + 2) * 32);
            }
        }
        mfma16<SWAP>(acc, a1, b1);
    }
}

// ---------------------------------------------------------------------------
// GEMM1: qkv = xb[8192][768] @ wqkvT^T, bf16. 128x128 tiles, 1152 blocks
// (64x18), XCD swizzle. q/k use SWAP (C^T: acc quartet runs along d) ->
// packed u16x4 stores; v normal -> packed u16x4 along tokens.
// ---------------------------------------------------------------------------
__global__ __launch_bounds__(256) void gemm_qkv(
    const u16* __restrict__ Aq, const u16* __restrict__ Bt,
    u16* __restrict__ qb, u16* __restrict__ kb, u16* __restrict__ vbT) {
    const int tid = threadIdx.x;
    const int lane = tid & 63, w = tid >> 6;
    const int m15 = lane & 15, quad = lane >> 4;
    const int wy = w >> 1, wx = w & 1;
    const int g = blockIdx.x;
    const int xcd = g & 7, s = g >> 3;               // s 0..143
    const int yt = xcd * 8 + (s & 7), xt = s >> 3;   // yt 0..63, xt 0..17
    const int m0 = yt * 128, n0 = xt * 128;
    const int which = xt / 6;                        // 0=q, 1=k, 2=v (block-uniform)

    f32x4 acc[4][4] = {};
    if (which < 2)
        gemm_l2_loop<true >(acc, Aq, Bt, m0, n0, lane, w);
    else
        gemm_l2_loop<false>(acc, Aq, Bt, m0, n0, lane, w);

    const int b   = m0 >> 10;
    const int r0  = (m0 & 1023) + wy * 64;
    const int n0p = n0 - which * 768;
    const int h   = (n0p >> 6) + wx;                 // wave-uniform head
    const size_t bhi = (size_t)(b * 12 + h);
    if (which == 2) {
        // normal orientation: quartet = 4 consecutive tokens, vbT token-minor
#pragma unroll
        for (int ri = 0; ri < 4; ++ri)
#pragma unroll
            for (int ci = 0; ci < 4; ++ci) {
                u16x4 pk;
#pragma unroll
                for (int rg = 0; rg < 4; ++rg) pk[rg] = f2bf(acc[ri][ci][rg]);
                const int d   = ci * 16 + m15;
                const int tok = r0 + ri * 16 + (quad << 2);
                *(u16x4*)&vbT[(bhi * 64 + d) * 1024 + tok] = pk;
            }
    } else {
        // swapped orientation: quartet = 4 consecutive d, qb/kb d-minor
        u16* dst = which ? kb : qb;
#pragma unroll
        for (int ri = 0; ri < 4; ++ri)
#pragma unroll
            for (int ci = 0; ci < 4; ++ci) {
                u16x4 pk;
#pragma unroll
                for (int rg = 0; rg < 4; ++rg) pk[rg] = f2bf(acc[ri][ci][rg]);
                const int tok = r0 + ri * 16 + m15;
                const int d   = ci * 16 + (quad << 2);
                *(u16x4*)&dst[(bhi * 1024 + tok) * 64 + d] = pk;
            }
    }
}

// ---------------------------------------------------------------------------
// GEMM2: out = aout[8192][768](bf16) @ wprojT^T + bias (fp32). Same loop.
// 384 blocks (64x6), XCD swizzle.
// ---------------------------------------------------------------------------
__global__ __launch_bounds__(256) void gemm_proj(
    const u16* __restrict__ A, const u16* __restrict__ Bt,
    const float* __restrict__ bias, float* __restrict__ out) {
    const int tid = threadIdx.x;
    const int lane = tid & 63, w = tid >> 6;
    const int m15 = lane & 15, quad = lane >> 4;
    const int wy = w >> 1, wx = w & 1;
    const int g = blockIdx.x;
    const int xcd = g & 7, s = g >> 3;               // s 0..47
    const int yt = xcd * 8 + (s & 7), xt = s >> 3;   // yt 0..63, xt 0..5
    const int m0 = yt * 128, n0 = xt * 128;

    f32x4 acc[4][4] = {};
    gemm_l2_loop<false>(acc, A, Bt, m0, n0, lane, w);

#pragma unroll
    for (int ri = 0; ri < 4; ++ri) {
        int mb = m0 + wy * 64 + ri * 16 + (quad << 2);
#pragma unroll
        for (int ci = 0; ci < 4; ++ci) {
            int n = n0 + wx * 64 + ci * 16 + m15;
            float bv_ = bias[n];
#pragma unroll
            for (int rg = 0; rg < 4; ++rg)
                out[(size_t)(mb + rg) * 768 + n] = acc[ri][ci][rg] + bv_;
        }
    }
}

// ---------------------------------------------------------------------------
// MFMA flash attention v3: S^T formulation.
//   S^T = K·Q^T (A=K-frag, B=Q-frag): C-reg quartet = 4 consecutive KEYS of
//   one query -> P written as packed b64 (4 ops, conflict-free) instead of 16
//   conflicted b16 stores; P read back as b128 A-frags (exact A layout).
//   2 query-sets per wave (32 q/wave, 128 q/block): K/V frag reads shared.
//   Fixed-max softmax (R4-verified), l via ones-column MFMA (unchanged).
// grid(768): xcd swizzle, 3 blocks/CU. LDS 36.9 KB.
// ---------------------------------------------------------------------------
#define KS 72   // LDS stride (64+8): b128/b64 accesses conflict-free

__global__ __launch_bounds__(256) void attn_mfma(
    const u16* __restrict__ qb, const u16* __restrict__ kb,
    const u16* __restrict__ vbT, u16* __restrict__ aout) {
    __shared__ __align__(16) u16 Ks[64 * KS];
    __shared__ __align__(16) u16 Vs[64 * KS];
    __shared__ __align__(16) u16 Ps[8][16 * KS];   // [wave*2+qs]
    const int tid = threadIdx.x, lane = tid & 63, w = tid >> 6;
    const int m15 = lane & 15, quad = lane >> 4;
    const int g = blockIdx.x;                      // 768 blocks
    const int xcd = g & 7, s = g >> 3;             // s 0..95
    const int bh = xcd * 12 + (s % 12);
    const int q0 = (s / 12) * 128;

    // Q B-frags (2 sets of 16 queries), in registers for the whole kernel
    s16x8 aq[2][2];
#pragma unroll
    for (int qs = 0; qs < 2; ++qs) {
        const u16* qp = qb + ((size_t)bh * 1024 + q0 + w * 32 + qs * 16 + m15) * 64 + quad * 8;
        aq[qs][0] = *(const s16x8*)qp;
        aq[qs][1] = *(const s16x8*)(qp + 32);
    }

    s16x8 bones;
#pragma unroll
    for (int j = 0; j < 8; ++j) bones[j] = (m15 == 0) ? (short)0x3F80 : (short)0;

    f32x4 oacc[2][4] = {};
    f32x4 lacc[2] = {};

    const int srow = tid >> 2;           // 0..63
    const int soff = (tid & 3) * 16;
    const u16* kbase = kb + (size_t)bh * 1024 * 64;
    const u16* vbase = vbT + (size_t)bh * 64 * 1024;
    const float CE   = 0.125f * 1.44269504f;   // SCALE * log2(e)
    const float MOFF = 12.0f * 1.44269504f;    // fixed max * log2(e)

    for (int kt = 0; kt < 16; ++kt) {
        __syncthreads();
        const u16* kpp = kbase + ((size_t)kt * 64 + srow) * 64 + soff;
        const u16* vpp = vbase + (size_t)srow * 1024 + kt * 64 + soff;
        *(u16x8*)&Ks[srow * KS + soff]     = *(const u16x8*)kpp;
        *(u16x8*)&Ks[srow * KS + soff + 8] = *(const u16x8*)(kpp + 8);
        *(u16x8*)&Vs[srow * KS + soff]     = *(const u16x8*)vpp;
        *(u16x8*)&Vs[srow * KS + soff + 8] = *(const u16x8*)(vpp + 8);
        __syncthreads();

        // --- S^T[key][q]: A = K rows, B = Q (both q-sets share K frags) ---
        f32x4 sacc[2][4] = {};
#pragma unroll
        for (int t = 0; t < 4; ++t)
#pragma unroll
            for (int ch = 0; ch < 2; ++ch) {
                s16x8 ak = *(const s16x8*)&Ks[(t * 16 + m15) * KS + quad * 8 + 32 * ch];
                sacc[0][t] = __builtin_amdgcn_mfma_f32_16x16x32_bf16(ak, aq[0][ch], sacc[0][t], 0, 0, 0);
                sacc[1][t] = __builtin_amdgcn_mfma_f32_16x16x32_bf16(ak, aq[1][ch], sacc[1][t], 0, 0, 0);
            }

        // --- P = exp2(s*CE - MOFF): 4 consecutive keys/reg -> packed b64 ---
#pragma unroll
        for (int qs = 0; qs < 2; ++qs)
#pragma unroll
            for (int t = 0; t < 4; ++t) {
                u16x4 pk;
#pragma unroll
                for (int reg = 0; reg < 4; ++reg) {
                    float pv = __builtin_amdgcn_exp2f(sacc[qs][t][reg] * CE - MOFF);
                    unsigned int u = __builtin_bit_cast(unsigned int, pv);
                    pk[reg] = (u16)(u >> 16);
                }
                *(u16x4*)&Ps[w * 2 + qs][m15 * KS + t * 16 + quad * 4] = pk;
            }
        // no barrier: Ps[w*2+qs] is wave-private

        // --- P A-frags, l (ones-column), PV (V frags shared across q-sets) ---
        s16x8 ap[2][2];
#pragma unroll
        for (int qs = 0; qs < 2; ++qs) {
            ap[qs][0] = *(const s16x8*)&Ps[w * 2 + qs][m15 * KS + quad * 8];
            ap[qs][1] = *(const s16x8*)&Ps[w * 2 + qs][m15 * KS + quad * 8 + 32];
#pragma unroll
            for (int ch = 0; ch < 2; ++ch)
                lacc[qs] = __builtin_amdgcn_mfma_f32_16x16x32_bf16(ap[qs][ch], bones, lacc[qs], 0, 0, 0);
        }
#pragma unroll
        for (int di = 0; di < 4; ++di)
#pragma unroll
            for (int ch = 0; ch < 2; ++ch) {
                s16x8 bv = *(const s16x8*)&Vs[(di * 16 + m15) * KS + quad * 8 + 32 * ch];
                oacc[0][di] = __builtin_amdgcn_mfma_f32_16x16x32_bf16(ap[0][ch], bv, oacc[0][di], 0, 0, 0);
                oacc[1][di] = __builtin_amdgcn_mfma_f32_16x16x32_bf16(ap[1][ch], bv, oacc[1][di], 0, 0, 0);
            }
    }

    const int b = bh / 12, h = bh - b * 12;
#pragma unroll
    for (int qs = 0; qs < 2; ++qs) {
        float linv[4];
#pragma unroll
        for (int reg = 0; reg < 4; ++reg)
            linv[reg] = 1.0f / __shfl(lacc[qs][reg], lane & 48);
#pragma unroll
        for (int di = 0; di < 4; ++di)
#pragma unroll
            for (int reg = 0; reg < 4; ++reg) {
                int q = q0 + w * 32 + qs * 16 + quad * 4 + reg;
                aout[((size_t)b * 1024 + q) * 768 + h * 64 + di * 16 + m15] =
                    f2bf(oacc[qs][di][reg] * linv[reg]);
            }
    }
}

// ---------------------------------------------------------------------------
extern "C" void kernel_launch(void* const* d_in, const int* in_sizes, int n_in,
                              void* d_out, int out_size, void* d_ws, size_t ws_size,
                              hipStream_t stream) {
    const float* x      = (const float*)d_in[0];
    const float* w_qkv  = (const float*)d_in[1];
    const float* w_proj = (const float*)d_in[2];
    const float* b_proj = (const float*)d_in[3];
    float* out = (float*)d_out;

    char* ws = (char*)d_ws;
    u16* wqkvT  = (u16*)ws;  ws += (size_t)2304 * 768 * 2;
    u16* wprojT = (u16*)ws;  ws += (size_t)768 * 768 * 2;
    u16* qb     = (u16*)ws;  ws += (size_t)96 * 1024 * 64 * 2;
    u16* kb     = (u16*)ws;  ws += (size_t)96 * 1024 * 64 * 2;
    u16* vbT    = (u16*)ws;  ws += (size_t)96 * 1024 * 64 * 2;
    u16* aout   = (u16*)ws;  ws += (size_t)8192 * 768 * 2;
    u16* xb     = aout;   // lifetimes don't overlap

    prep<<<dim3(5376), 256, 0, stream>>>(x, xb, w_qkv, wqkvT, w_proj, wprojT);
    gemm_qkv<<<dim3(1152), 256, 0, stream>>>(xb, wqkvT, qb, kb, vbT);
    attn_mfma<<<dim3(768), 256, 0, stream>>>(qb, kb, vbT, aout);
    gemm_proj<<<dim3(384), 256, 0, stream>>>(aout, wprojT, b_proj, out);
}

// Round 4
// 189.225 us; speedup vs baseline: 1.5057x; 1.5057x over previous
//
#include <hip/hip_runtime.h>

// Problem: B=8, N=1024, C=768, H=12, D=64. Inputs fp32; internal bf16 MFMA.
// ws layout: wqkvT bf16[2304][768] | wprojT bf16[768][768] |
//   q,k bf16[B*H][N][D], vT bf16[B*H][D][N] | aout bf16[8192][768] (aliased as xb)

typedef unsigned short u16;
typedef short s16x8 __attribute__((ext_vector_type(8)));   // 8 bf16 = 4 VGPRs
typedef float f32x4 __attribute__((ext_vector_type(4)));
typedef u16   u16x8 __attribute__((ext_vector_type(8)));
typedef u16   u16x4 __attribute__((ext_vector_type(4)));

__device__ __forceinline__ u16 f2bf(float f) {
    unsigned int u = __builtin_bit_cast(unsigned int, f);
    u += 0x7FFFu + ((u >> 16) & 1u);      // RNE
    return (u16)(u >> 16);
}

// async global->LDS, 16B per lane. LDS dest must be WAVE-UNIFORM base;
// HW adds lane*16 (m97/m104-verified semantics).
__device__ __forceinline__ void gload16(const u16* g, u16* l) {
    __builtin_amdgcn_global_load_lds(
        (const __attribute__((address_space(1))) unsigned int*)g,
        (__attribute__((address_space(3))) unsigned int*)l, 16, 0, 0);
}

// ---------------------------------------------------------------------------
// Fused prep: x fp32->bf16 convert (blocks 0..3071) | w_qkv transpose
// (3072..4799) | w_proj transpose (4800..5375).
// ---------------------------------------------------------------------------
__global__ __launch_bounds__(256) void prep(
    const float* __restrict__ x, u16* __restrict__ xb,
    const float* __restrict__ wq, u16* __restrict__ wqT,
    const float* __restrict__ wp, u16* __restrict__ wpT) {
    __shared__ float ts[32][33];
    const int g = blockIdx.x, tid = threadIdx.x;
    if (g < 3072) {
        const size_t i = ((size_t)g * 256 + tid) * 8;
        float4 v0 = *(const float4*)(x + i);
        float4 v1 = *(const float4*)(x + i + 4);
        u16x8 p;
        p[0] = f2bf(v0.x); p[1] = f2bf(v0.y); p[2] = f2bf(v0.z); p[3] = f2bf(v0.w);
        p[4] = f2bf(v1.x); p[5] = f2bf(v1.y); p[6] = f2bf(v1.z); p[7] = f2bf(v1.w);
        *(u16x8*)(xb + i) = p;
        return;
    }
    const float* in; u16* out; int K, Nc, n0, k0;
    if (g < 4800) {
        int gg = g - 3072; in = wq; out = wqT; K = 768; Nc = 2304;
        n0 = (gg % 72) * 32; k0 = (gg / 72) * 32;
    } else {
        int gg = g - 4800; in = wp; out = wpT; K = 768; Nc = 768;
        n0 = (gg % 24) * 32; k0 = (gg / 24) * 32;
    }
    const int tx = tid & 31, ty = tid >> 5;
#pragma unroll
    for (int j = 0; j < 4; ++j) {
        int r = ty + j * 8;
        ts[r][tx] = in[(size_t)(k0 + r) * Nc + n0 + tx];
    }
    __syncthreads();
#pragma unroll
    for (int j = 0; j < 4; ++j) {
        int r = ty + j * 8;
        out[(size_t)(n0 + r) * K + k0 + tx] = f2bf(ts[tx][r]);
    }
}

// ---------------------------------------------------------------------------
// Shared 128x128 GEMM K-loop: BK=32, depth-2 counted-vmcnt TRIPLE buffer.
// R2 (depth-1, vmcnt(4)) = 52.8us/530TF: latency coverage was one step time;
// loaded L2/HBM latency (~600-900cy, m126) exceeds it. Depth-2 doubles the
// coverage: stage(s+2) issued two steps before its wait. vmcnt(8) = 2 tiles
// (8 loads/wave) stay in flight; never 0 in the loop (T4).
// Per step: stage s+2 -> vmcnt(8) -> barrier -> 8 ds_read_b128 -> 16 MFMA
// (setprio) -> barrier. Zero-conflict XOR swizzle (R1/R2-verified: 0).
// Race-freedom: stage(s+2) overwrites buf[(s+2)%3]=buf[(s-1)%3], last read
// at step s-1; those ds_reads complete before s-1's MFMA (compiler lgkm),
// before s-1's end barrier, before this stage is issued at step s.
// LDS 48KB -> 3 blocks/CU co-resident (m114 overlap engine).
// ---------------------------------------------------------------------------
template<bool SWAP>
__device__ __forceinline__ void gemm_loop_128(
    f32x4 (&acc)[4][4], const u16* __restrict__ A, const u16* __restrict__ B,
    u16* As, u16* Bs, int m0, int n0, int lane, int w) {
    const int m15 = lane & 15, quad = lane >> 4;
    const int wy = w >> 1, wx = w & 1;
    const int qsw8 = (quad ^ ((m15 >> 1) & 3)) * 8;        // read-side swizzle
    const int srow16 = lane >> 2;                           // 0..15
    const int scg = ((lane & 3) ^ ((lane >> 3) & 3)) * 8;  // staged-source swizzle
    const size_t gA = (size_t)(m0 + w * 32 + srow16) * 768 + scg;
    const size_t gB = (size_t)(n0 + w * 32 + srow16) * 768 + scg;

    auto stage = [&](int buf, int s) {
        const int k0 = (s < 24 ? s : 0) * 32;   // wrap: harmless garbage, uniform count
        u16* da = As + buf * 4096 + (w * 32) * 32;
        u16* db = Bs + buf * 4096 + (w * 32) * 32;
        gload16(A + gA + k0,            da);
        gload16(A + gA + 16 * 768 + k0, da + 16 * 32);
        gload16(B + gB + k0,            db);
        gload16(B + gB + 16 * 768 + k0, db + 16 * 32);
    };

    stage(0, 0);
    stage(1, 1);
    const int arow = (wy * 64 + m15) * 32 + qsw8;   // + ri*512
    const int brow = (wx * 64 + m15) * 32 + qsw8;   // + ci*512

#pragma unroll 3
    for (int s = 0; s < 24; ++s) {
        const int cur = s % 3;
        stage((s + 2) % 3, s + 2);
        asm volatile("s_waitcnt vmcnt(8)" ::: "memory");   // tile s landed; s+1,s+2 in flight
        __builtin_amdgcn_s_barrier();
        const u16* Ap = As + cur * 4096;
        const u16* Bp = Bs + cur * 4096;
        s16x8 av[4], bv[4];
#pragma unroll
        for (int ri = 0; ri < 4; ++ri)
            av[ri] = *(const s16x8*)(Ap + arow + ri * 512);
#pragma unroll
        for (int ci = 0; ci < 4; ++ci)
            bv[ci] = *(const s16x8*)(Bp + brow + ci * 512);
        __builtin_amdgcn_s_setprio(1);
#pragma unroll
        for (int ri = 0; ri < 4; ++ri)
#pragma unroll
            for (int ci = 0; ci < 4; ++ci) {
                if (SWAP)
                    acc[ri][ci] = __builtin_amdgcn_mfma_f32_16x16x32_bf16(bv[ci], av[ri], acc[ri][ci], 0, 0, 0);
                else
                    acc[ri][ci] = __builtin_amdgcn_mfma_f32_16x16x32_bf16(av[ri], bv[ci], acc[ri][ci], 0, 0, 0);
            }
        __builtin_amdgcn_s_setprio(0);
        __builtin_amdgcn_s_barrier();
    }
    asm volatile("s_waitcnt vmcnt(0)" ::: "memory");  // drain tail garbage loads
}

// ---------------------------------------------------------------------------
// GEMM1: qkv = xb[8192][768] @ wqkvT^T, bf16. 128x128 tiles, 1152 blocks
// (64x18), XCD swizzle, 3 blocks/CU. q/k use SWAP (C^T: acc quartet runs
// along d) -> packed u16x4 stores; v normal -> packed u16x4 along tokens.
// ---------------------------------------------------------------------------
__global__ __launch_bounds__(256, 3) void gemm_qkv(
    const u16* __restrict__ Aq, const u16* __restrict__ Bt,
    u16* __restrict__ qb, u16* __restrict__ kb, u16* __restrict__ vbT) {
    __shared__ __align__(16) u16 As[3 * 128 * 32];   // 24KB
    __shared__ __align__(16) u16 Bs[3 * 128 * 32];   // 24KB
    const int tid = threadIdx.x;
    const int lane = tid & 63, w = tid >> 6;
    const int m15 = lane & 15, quad = lane >> 4;
    const int wy = w >> 1, wx = w & 1;
    const int g = blockIdx.x;
    const int xcd = g & 7, s = g >> 3;               // s 0..143
    const int yt = xcd * 8 + (s & 7), xt = s >> 3;   // yt 0..63, xt 0..17
    const int m0 = yt * 128, n0 = xt * 128;
    const int which = xt / 6;                        // 0=q, 1=k, 2=v (block-uniform)

    f32x4 acc[4][4] = {};
    if (which < 2)
        gemm_loop_128<true >(acc, Aq, Bt, As, Bs, m0, n0, lane, w);
    else
        gemm_loop_128<false>(acc, Aq, Bt, As, Bs, m0, n0, lane, w);

    const int b   = m0 >> 10;
    const int r0  = (m0 & 1023) + wy * 64;
    const int n0p = n0 - which * 768;
    const int h   = (n0p >> 6) + wx;                 // wave-uniform head
    const size_t bhi = (size_t)(b * 12 + h);
    if (which == 2) {
        // normal orientation: quartet = 4 consecutive tokens, vbT token-minor
#pragma unroll
        for (int ri = 0; ri < 4; ++ri)
#pragma unroll
            for (int ci = 0; ci < 4; ++ci) {
                u16x4 pk;
#pragma unroll
                for (int rg = 0; rg < 4; ++rg) pk[rg] = f2bf(acc[ri][ci][rg]);
                const int d   = ci * 16 + m15;
                const int tok = r0 + ri * 16 + (quad << 2);
                *(u16x4*)&vbT[(bhi * 64 + d) * 1024 + tok] = pk;
            }
    } else {
        // swapped orientation: quartet = 4 consecutive d, qb/kb d-minor
        u16* dst = which ? kb : qb;
#pragma unroll
        for (int ri = 0; ri < 4; ++ri)
#pragma unroll
            for (int ci = 0; ci < 4; ++ci) {
                u16x4 pk;
#pragma unroll
                for (int rg = 0; rg < 4; ++rg) pk[rg] = f2bf(acc[ri][ci][rg]);
                const int tok = r0 + ri * 16 + m15;
                const int d   = ci * 16 + (quad << 2);
                *(u16x4*)&dst[(bhi * 1024 + tok) * 64 + d] = pk;
            }
    }
}

// ---------------------------------------------------------------------------
// GEMM2: out = aout[8192][768](bf16) @ wprojT^T + bias (fp32). Same loop.
// 384 blocks (64x6), XCD swizzle, 3 blocks/CU.
// ---------------------------------------------------------------------------
__global__ __launch_bounds__(256, 3) void gemm_proj(
    const u16* __restrict__ A, const u16* __restrict__ Bt,
    const float* __restrict__ bias, float* __restrict__ out) {
    __shared__ __align__(16) u16 As[3 * 128 * 32];
    __shared__ __align__(16) u16 Bs[3 * 128 * 32];
    const int tid = threadIdx.x;
    const int lane = tid & 63, w = tid >> 6;
    const int m15 = lane & 15, quad = lane >> 4;
    const int wy = w >> 1, wx = w & 1;
    const int g = blockIdx.x;
    const int xcd = g & 7, s = g >> 3;               // s 0..47
    const int yt = xcd * 8 + (s & 7), xt = s >> 3;   // yt 0..63, xt 0..5
    const int m0 = yt * 128, n0 = xt * 128;

    f32x4 acc[4][4] = {};
    gemm_loop_128<false>(acc, A, Bt, As, Bs, m0, n0, lane, w);

#pragma unroll
    for (int ri = 0; ri < 4; ++ri) {
        int mb = m0 + wy * 64 + ri * 16 + (quad << 2);
#pragma unroll
        for (int ci = 0; ci < 4; ++ci) {
            int n = n0 + wx * 64 + ci * 16 + m15;
            float bv_ = bias[n];
#pragma unroll
            for (int rg = 0; rg < 4; ++rg)
                out[(size_t)(mb + rg) * 768 + n] = acc[ri][ci][rg] + bv_;
        }
    }
}

// ---------------------------------------------------------------------------
// MFMA flash attention v3: S^T formulation.
//   S^T = K·Q^T (A=K-frag, B=Q-frag): C-reg quartet = 4 consecutive KEYS of
//   one query -> P written as packed b64 (4 ops, conflict-free) instead of 16
//   conflicted b16 stores; P read back as b128 A-frags (exact A layout).
//   2 query-sets per wave (32 q/wave, 128 q/block): K/V frag reads shared.
//   Fixed-max softmax (R4-verified), l via ones-column MFMA (unchanged).
// grid(768): xcd swizzle, 3 blocks/CU. LDS 36.9 KB.
// ---------------------------------------------------------------------------
#define KS 72   // LDS stride (64+8): b128/b64 accesses conflict-free

__global__ __launch_bounds__(256) void attn_mfma(
    const u16* __restrict__ qb, const u16* __restrict__ kb,
    const u16* __restrict__ vbT, u16* __restrict__ aout) {
    __shared__ __align__(16) u16 Ks[64 * KS];
    __shared__ __align__(16) u16 Vs[64 * KS];
    __shared__ __align__(16) u16 Ps[8][16 * KS];   // [wave*2+qs]
    const int tid = threadIdx.x, lane = tid & 63, w = tid >> 6;
    const int m15 = lane & 15, quad = lane >> 4;
    const int g = blockIdx.x;                      // 768 blocks
    const int xcd = g & 7, s = g >> 3;             // s 0..95
    const int bh = xcd * 12 + (s % 12);
    const int q0 = (s / 12) * 128;

    // Q B-frags (2 sets of 16 queries), in registers for the whole kernel
    s16x8 aq[2][2];
#pragma unroll
    for (int qs = 0; qs < 2; ++qs) {
        const u16* qp = qb + ((size_t)bh * 1024 + q0 + w * 32 + qs * 16 + m15) * 64 + quad * 8;
        aq[qs][0] = *(const s16x8*)qp;
        aq[qs][1] = *(const s16x8*)(qp + 32);
    }

    s16x8 bones;
#pragma unroll
    for (int j = 0; j < 8; ++j) bones[j] = (m15 == 0) ? (short)0x3F80 : (short)0;

    f32x4 oacc[2][4] = {};
    f32x4 lacc[2] = {};

    const int srow = tid >> 2;           // 0..63
    const int soff = (tid & 3) * 16;
    const u16* kbase = kb + (size_t)bh * 1024 * 64;
    const u16* vbase = vbT + (size_t)bh * 64 * 1024;
    const float CE   = 0.125f * 1.44269504f;   // SCALE * log2(e)
    const float MOFF = 12.0f * 1.44269504f;    // fixed max * log2(e)

    for (int kt = 0; kt < 16; ++kt) {
        __syncthreads();
        const u16* kpp = kbase + ((size_t)kt * 64 + srow) * 64 + soff;
        const u16* vpp = vbase + (size_t)srow * 1024 + kt * 64 + soff;
        *(u16x8*)&Ks[srow * KS + soff]     = *(const u16x8*)kpp;
        *(u16x8*)&Ks[srow * KS + soff + 8] = *(const u16x8*)(kpp + 8);
        *(u16x8*)&Vs[srow * KS + soff]     = *(const u16x8*)vpp;
        *(u16x8*)&Vs[srow * KS + soff + 8] = *(const u16x8*)(vpp + 8);
        __syncthreads();

        // --- S^T[key][q]: A = K rows, B = Q (both q-sets share K frags) ---
        f32x4 sacc[2][4] = {};
#pragma unroll
        for (int t = 0; t < 4; ++t)
#pragma unroll
            for (int ch = 0; ch < 2; ++ch) {
                s16x8 ak = *(const s16x8*)&Ks[(t * 16 + m15) * KS + quad * 8 + 32 * ch];
                sacc[0][t] = __builtin_amdgcn_mfma_f32_16x16x32_bf16(ak, aq[0][ch], sacc[0][t], 0, 0, 0);
                sacc[1][t] = __builtin_amdgcn_mfma_f32_16x16x32_bf16(ak, aq[1][ch], sacc[1][t], 0, 0, 0);
            }

        // --- P = exp2(s*CE - MOFF): 4 consecutive keys/reg -> packed b64 ---
#pragma unroll
        for (int qs = 0; qs < 2; ++qs)
#pragma unroll
            for (int t = 0; t < 4; ++t) {
                u16x4 pk;
#pragma unroll
                for (int reg = 0; reg < 4; ++reg) {
                    float pv = __builtin_amdgcn_exp2f(sacc[qs][t][reg] * CE - MOFF);
                    unsigned int u = __builtin_bit_cast(unsigned int, pv);
                    pk[reg] = (u16)(u >> 16);
                }
                *(u16x4*)&Ps[w * 2 + qs][m15 * KS + t * 16 + quad * 4] = pk;
            }
        // no barrier: Ps[w*2+qs] is wave-private

        // --- P A-frags, l (ones-column), PV (V frags shared across q-sets) ---
        s16x8 ap[2][2];
#pragma unroll
        for (int qs = 0; qs < 2; ++qs) {
            ap[qs][0] = *(const s16x8*)&Ps[w * 2 + qs][m15 * KS + quad * 8];
            ap[qs][1] = *(const s16x8*)&Ps[w * 2 + qs][m15 * KS + quad * 8 + 32];
#pragma unroll
            for (int ch = 0; ch < 2; ++ch)
                lacc[qs] = __builtin_amdgcn_mfma_f32_16x16x32_bf16(ap[qs][ch], bones, lacc[qs], 0, 0, 0);
        }
#pragma unroll
        for (int di = 0; di < 4; ++di)
#pragma unroll
            for (int ch = 0; ch < 2; ++ch) {
                s16x8 bv = *(const s16x8*)&Vs[(di * 16 + m15) * KS + quad * 8 + 32 * ch];
                oacc[0][di] = __builtin_amdgcn_mfma_f32_16x16x32_bf16(ap[0][ch], bv, oacc[0][di], 0, 0, 0);
                oacc[1][di] = __builtin_amdgcn_mfma_f32_16x16x32_bf16(ap[1][ch], bv, oacc[1][di], 0, 0, 0);
            }
    }

    const int b = bh / 12, h = bh - b * 12;
#pragma unroll
    for (int qs = 0; qs < 2; ++qs) {
        float linv[4];
#pragma unroll
        for (int reg = 0; reg < 4; ++reg)
            linv[reg] = 1.0f / __shfl(lacc[qs][reg], lane & 48);
#pragma unroll
        for (int di = 0; di < 4; ++di)
#pragma unroll
            for (int reg = 0; reg < 4; ++reg) {
                int q = q0 + w * 32 + qs * 16 + quad * 4 + reg;
                aout[((size_t)b * 1024 + q) * 768 + h * 64 + di * 16 + m15] =
                    f2bf(oacc[qs][di][reg] * linv[reg]);
            }
    }
}

// ---------------------------------------------------------------------------
extern "C" void kernel_launch(void* const* d_in, const int* in_sizes, int n_in,
                              void* d_out, int out_size, void* d_ws, size_t ws_size,
                              hipStream_t stream) {
    const float* x      = (const float*)d_in[0];
    const float* w_qkv  = (const float*)d_in[1];
    const float* w_proj = (const float*)d_in[2];
    const float* b_proj = (const float*)d_in[3];
    float* out = (float*)d_out;

    char* ws = (char*)d_ws;
    u16* wqkvT  = (u16*)ws;  ws += (size_t)2304 * 768 * 2;
    u16* wprojT = (u16*)ws;  ws += (size_t)768 * 768 * 2;
    u16* qb     = (u16*)ws;  ws += (size_t)96 * 1024 * 64 * 2;
    u16* kb     = (u16*)ws;  ws += (size_t)96 * 1024 * 64 * 2;
    u16* vbT    = (u16*)ws;  ws += (size_t)96 * 1024 * 64 * 2;
    u16* aout   = (u16*)ws;  ws += (size_t)8192 * 768 * 2;
    u16* xb     = aout;   // lifetimes don't overlap

    prep<<<dim3(5376), 256, 0, stream>>>(x, xb, w_qkv, wqkvT, w_proj, wprojT);
    gemm_qkv<<<dim3(1152), 256, 0, stream>>>(xb, wqkvT, qb, kb, vbT);
    attn_mfma<<<dim3(768), 256, 0, stream>>>(qb, kb, vbT, aout);
    gemm_proj<<<dim3(384), 256, 0, stream>>>(aout, wprojT, b_proj, out);
}